// Round 1
// baseline (170.216 us; speedup 1.0000x reference)
//
#include <hip/hip_runtime.h>
#include <math.h>

// Attn_83854941487646: out = softmax(tanh(Q) @ H^T) @ H
// B=8, Q=2048, K=2048, Hdim=128, fp32 in/out. Flash-style fused, f16 MFMA.

typedef _Float16 half8 __attribute__((ext_vector_type(8)));
typedef _Float16 half4 __attribute__((ext_vector_type(4)));
typedef float    f32x4 __attribute__((ext_vector_type(4)));

#define QQ 2048
#define KK 2048
#define HH 128
#define BM 64          // query rows per block
#define BN 64          // key rows per tile
#define KS_STR 136     // Ks row stride in halves (128 + 8 pad) -> conflict-free
#define VT_STR 72      // Vt row stride in halves (64 + 8 pad)  -> conflict-free
#define PS_STR 72      // Ps row stride in halves

__launch_bounds__(256, 1)
__global__ void attn_kernel(const float* __restrict__ out_state,
                            const float* __restrict__ history,
                            float* __restrict__ out) {
    // LDS: K-tile row-major (for QK^T B-frags, h-contiguous reads) and
    // transposed copy Vt[h][n] (for PV B-frags, n-contiguous reads).
    __shared__ _Float16 Ks[BN * KS_STR];        // 17408 B
    __shared__ _Float16 Vt[HH * VT_STR];        // 18432 B
    __shared__ _Float16 Ps[4][16 * PS_STR];     //  9216 B (per-wave P tiles)

    const int tid  = threadIdx.x;
    const int wave = tid >> 6;
    const int lane = tid & 63;
    const int quad = lane >> 4;
    const int lc   = lane & 15;

    const int b      = blockIdx.x >> 5;   // 0..7   (32 consecutive blocks share a batch -> L2 reuse)
    const int qblock = blockIdx.x & 31;   // 0..31
    const int m0     = qblock * BM;

    // ---- persistent Q fragments: A[m=lc][k=quad*8+j], k-chunk s covers h=32s..32s+31 ----
    half8 qf[4];
    {
        const int m = m0 + wave * 16 + lc;
        const float* qrow = out_state + ((size_t)b * QQ + m) * HH;
        #pragma unroll
        for (int s = 0; s < 4; ++s) {
            const int h0 = 32 * s + quad * 8;
            const float4 a = *(const float4*)(qrow + h0);
            const float4 c = *(const float4*)(qrow + h0 + 4);
            qf[s][0] = (_Float16)tanhf(a.x); qf[s][1] = (_Float16)tanhf(a.y);
            qf[s][2] = (_Float16)tanhf(a.z); qf[s][3] = (_Float16)tanhf(a.w);
            qf[s][4] = (_Float16)tanhf(c.x); qf[s][5] = (_Float16)tanhf(c.y);
            qf[s][6] = (_Float16)tanhf(c.z); qf[s][7] = (_Float16)tanhf(c.w);
        }
    }

    const f32x4 zero4 = {0.f, 0.f, 0.f, 0.f};
    f32x4 O[8];                                  // O[ct]: rows quad*4+r, cols 16*ct+lc
    #pragma unroll
    for (int i = 0; i < 8; ++i) O[i] = zero4;
    float rmax[4] = {-3.0e38f, -3.0e38f, -3.0e38f, -3.0e38f};
    float rsum[4] = {0.f, 0.f, 0.f, 0.f};

    // staging thread mappings
    const int r0  = tid >> 5;          // stage1: key-row base (0..7), +8j
    const int c4  = (tid & 31) * 4;    // stage1: h column (float4)
    const int th  = tid & 127;         // stage2: h row of Vt
    const int tnb = (tid >> 7) * 32;   // stage2: n base (0 or 32)

    for (int kt = 0; kt < KK / BN; ++kt) {
        const int n0 = kt * BN;

        // stage 0: coalesced global prefetch of history tile into regs
        float4 g[8];
        const float* hb = history + ((size_t)b * KK + n0) * HH;
        #pragma unroll
        for (int j = 0; j < 8; ++j)
            g[j] = *(const float4*)(hb + (size_t)(r0 + 8 * j) * HH + c4);

        __syncthreads();                      // previous tile's compute done
        // stage 1: Ks row-major (f16)
        #pragma unroll
        for (int j = 0; j < 8; ++j) {
            half4 hv;
            hv[0] = (_Float16)g[j].x; hv[1] = (_Float16)g[j].y;
            hv[2] = (_Float16)g[j].z; hv[3] = (_Float16)g[j].w;
            *(half4*)&Ks[(r0 + 8 * j) * KS_STR + c4] = hv;
        }
        __syncthreads();                      // Ks ready
        // stage 2: transpose Ks -> Vt[h][n] (column reads broadcast-free, b128 writes conflict-free)
        #pragma unroll
        for (int p = 0; p < 4; ++p) {
            half8 tv;
            #pragma unroll
            for (int j = 0; j < 8; ++j)
                tv[j] = Ks[(tnb + 8 * p + j) * KS_STR + th];
            *(half8*)&Vt[th * VT_STR + tnb + 8 * p] = tv;
        }
        __syncthreads();                      // Vt ready

        // ---- S = tanh(Q) K^T : C-layout row m=quad*4+r, col n=16*nt+lc ----
        f32x4 S[4];
        #pragma unroll
        for (int nt = 0; nt < 4; ++nt) {
            f32x4 acc = zero4;
            #pragma unroll
            for (int s = 0; s < 4; ++s) {
                half8 kf = *(half8*)&Ks[(nt * 16 + lc) * KS_STR + 32 * s + quad * 8];
                acc = __builtin_amdgcn_mfma_f32_16x16x32_f16(qf[s], kf, acc, 0, 0, 0);
            }
            S[nt] = acc;
        }

        // ---- online softmax (rows live across the 16 lanes of each quad) ----
        float tmax[4];
        #pragma unroll
        for (int r = 0; r < 4; ++r)
            tmax[r] = fmaxf(fmaxf(S[0][r], S[1][r]), fmaxf(S[2][r], S[3][r]));
        #pragma unroll
        for (int d = 1; d < 16; d <<= 1) {
            #pragma unroll
            for (int r = 0; r < 4; ++r)
                tmax[r] = fmaxf(tmax[r], __shfl_xor(tmax[r], d, 16));
        }
        float alpha[4], psum[4];
        #pragma unroll
        for (int r = 0; r < 4; ++r) {
            float nm = fmaxf(rmax[r], tmax[r]);
            alpha[r] = exp2f((rmax[r] - nm) * 1.44269504f);
            rmax[r] = nm;
            psum[r] = 0.f;
        }
        #pragma unroll
        for (int nt = 0; nt < 4; ++nt) {
            #pragma unroll
            for (int r = 0; r < 4; ++r) {
                float p = exp2f((S[nt][r] - rmax[r]) * 1.44269504f);
                S[nt][r] = p;
                psum[r] += p;
            }
        }
        #pragma unroll
        for (int d = 1; d < 16; d <<= 1) {
            #pragma unroll
            for (int r = 0; r < 4; ++r)
                psum[r] += __shfl_xor(psum[r], d, 16);
        }
        #pragma unroll
        for (int r = 0; r < 4; ++r)
            rsum[r] = rsum[r] * alpha[r] + psum[r];

        // rescale accumulator
        #pragma unroll
        for (int ct = 0; ct < 8; ++ct) {
            #pragma unroll
            for (int r = 0; r < 4; ++r)
                O[ct][r] *= alpha[r];
        }

        // ---- P: C-layout -> per-wave LDS (A-layout consumable). Same-wave DS ops are in-order. ----
        #pragma unroll
        for (int nt = 0; nt < 4; ++nt) {
            #pragma unroll
            for (int r = 0; r < 4; ++r)
                Ps[wave][(quad * 4 + r) * PS_STR + nt * 16 + lc] = (_Float16)S[nt][r];
        }

        // ---- O += P V : A[m=lc][n=32*s2+quad*8+j], B from Vt (n-contiguous) ----
        #pragma unroll
        for (int s2 = 0; s2 < 2; ++s2) {
            half8 af = *(half8*)&Ps[wave][lc * PS_STR + 32 * s2 + quad * 8];
            #pragma unroll
            for (int ct = 0; ct < 8; ++ct) {
                half8 vf = *(half8*)&Vt[(ct * 16 + lc) * VT_STR + 32 * s2 + quad * 8];
                O[ct] = __builtin_amdgcn_mfma_f32_16x16x32_f16(af, vf, O[ct], 0, 0, 0);
            }
        }
    }

    // ---- epilogue: normalize by row sums, store fp32 ----
    const int mrow = m0 + wave * 16 + quad * 4;
    float* orow = out + ((size_t)b * QQ + mrow) * HH;
    #pragma unroll
    for (int r = 0; r < 4; ++r) {
        float inv = 1.0f / rsum[r];
        #pragma unroll
        for (int ct = 0; ct < 8; ++ct)
            orow[(size_t)r * HH + ct * 16 + lc] = O[ct][r] * inv;
    }
}

extern "C" void kernel_launch(void* const* d_in, const int* in_sizes, int n_in,
                              void* d_out, int out_size, void* d_ws, size_t ws_size,
                              hipStream_t stream) {
    const float* out_state = (const float*)d_in[0];   // [8,2048,128] fp32
    const float* history   = (const float*)d_in[1];   // [8,2048,128] fp32
    float* out = (float*)d_out;                       // [8,2048,128] fp32
    attn_kernel<<<dim3(256), dim3(256), 0, stream>>>(out_state, history, out);
}

// Round 2
// 117.800 us; speedup vs baseline: 1.4450x; 1.4450x over previous
//
#include <hip/hip_runtime.h>
#include <math.h>

// Attn_83854941487646: out = softmax(tanh(Q) @ H^T) @ H
// B=8, Q=2048, K=2048, Hdim=128, fp32 in/out.
// R2: flash split-K (occupancy fix) + transposed compute S^T/O^T (cheap softmax)
//     + ones-MFMA rowsum + b32-pair LDS transpose.

typedef _Float16 half8 __attribute__((ext_vector_type(8)));
typedef _Float16 half4 __attribute__((ext_vector_type(4)));
typedef float    f32x4 __attribute__((ext_vector_type(4)));

#define QQ 2048
#define KK 2048
#define HH 128
#define BM 64
#define BN 64
#define NTILES 32            // KK / BN
#define KS_STR 136           // Ks row stride (halves): 128 + 8 pad
#define VT_STR 72            // Vt row stride (halves): 64 + 8 pad
#define PS_STR 72            // Ps row stride (halves)
#define L2E 1.44269504f
#define SPLITS_TARGET 3
// ws bytes per split: O partial 256*64*128 f32 + m 256*64 + l 256*64
#define WS_O_FLOATS   ((size_t)256 * BM * HH)       // per split
#define WS_ML_FLOATS  ((size_t)256 * BM)            // per split, each of m,l

union U32H { unsigned int u; _Float16 h[2]; };

__launch_bounds__(256, 3)
__global__ void attn_main(const float* __restrict__ out_state,
                          const float* __restrict__ history,
                          float* __restrict__ out,
                          float* __restrict__ ws,
                          int splits) {
    __shared__ _Float16 Ks[BN * KS_STR];        // 17408 B  row-major K tile
    __shared__ _Float16 Vt[HH * VT_STR];        // 18432 B  transposed [h][n]
    __shared__ _Float16 Ps[4][16 * PS_STR];     //  9216 B  per-wave P [qrow][key]

    const int tid  = threadIdx.x;
    const int wave = tid >> 6;
    const int lane = tid & 63;
    const int quad = lane >> 4;
    const int lc   = lane & 15;

    const int bid  = blockIdx.x;
    const int s    = bid >> 8;          // split id (grid = 256*splits)
    const int r256 = bid & 255;
    const int b    = r256 >> 5;
    const int qb   = r256 & 31;
    const int m0   = qb * BM;

    const int kt0 = (NTILES * s) / splits;
    const int kt1 = (NTILES * (s + 1)) / splits;

    // ---- Q fragment (used as MFMA *B* operand for S^T = K . Q^T):
    //      lane holds Q[m=lc][k=quad*8+j] == Q^T[k][n=lc] -- identical bits.
    half8 qf[4];
    {
        const int m = m0 + wave * 16 + lc;
        const float* qrow = out_state + ((size_t)b * QQ + m) * HH;
        #pragma unroll
        for (int s4 = 0; s4 < 4; ++s4) {
            const int h0 = 32 * s4 + quad * 8;
            const float4 a = *(const float4*)(qrow + h0);
            const float4 c = *(const float4*)(qrow + h0 + 4);
            qf[s4][0] = (_Float16)tanhf(a.x); qf[s4][1] = (_Float16)tanhf(a.y);
            qf[s4][2] = (_Float16)tanhf(a.z); qf[s4][3] = (_Float16)tanhf(a.w);
            qf[s4][4] = (_Float16)tanhf(c.x); qf[s4][5] = (_Float16)tanhf(c.y);
            qf[s4][6] = (_Float16)tanhf(c.z); qf[s4][7] = (_Float16)tanhf(c.w);
        }
    }

    const f32x4 zero4 = {0.f, 0.f, 0.f, 0.f};
    f32x4 O[8];                 // O^T tile ct: rows h=16ct+quad*4+r, col qrow=lc
    #pragma unroll
    for (int i = 0; i < 8; ++i) O[i] = zero4;
    f32x4 Osum = zero4;         // running row-sum (per col qrow=lc, regs redundant)
    float rmax = -3.0e38f;      // running max for this lane's q-row (replicated/quad)

    // staging maps
    const int r0  = tid >> 5;           // stage1 key-row base
    const int c4  = (tid & 31) * 4;     // stage1 h col (float4)
    const int h0  = 2 * (tid & 63);     // stage2: this thread's h-pair
    const int n0t = (tid >> 6) * 16;    // stage2: 16-key group

    const half8 ones = {(_Float16)1.f,(_Float16)1.f,(_Float16)1.f,(_Float16)1.f,
                        (_Float16)1.f,(_Float16)1.f,(_Float16)1.f,(_Float16)1.f};

    for (int kt = kt0; kt < kt1; ++kt) {
        const int n0 = kt * BN;

        // stage 0: coalesced global prefetch
        float4 g[8];
        const float* hb = history + ((size_t)b * KK + n0) * HH;
        #pragma unroll
        for (int j = 0; j < 8; ++j)
            g[j] = *(const float4*)(hb + (size_t)(r0 + 8 * j) * HH + c4);

        __syncthreads();                 // previous tile's compute done
        // stage 1: Ks row-major f16
        #pragma unroll
        for (int j = 0; j < 8; ++j) {
            half4 hv;
            hv[0] = (_Float16)g[j].x; hv[1] = (_Float16)g[j].y;
            hv[2] = (_Float16)g[j].z; hv[3] = (_Float16)g[j].w;
            *(half4*)&Ks[(r0 + 8 * j) * KS_STR + c4] = hv;
        }
        __syncthreads();                 // Ks ready
        // stage 2: transpose via b32-pair reads (rows h0,h0+1 x keys n0t..n0t+15)
        {
            half8 ra0, ra1, rb0, rb1;
            #pragma unroll
            for (int i = 0; i < 8; ++i) {
                U32H t; t.u = *(const unsigned int*)&Ks[(n0t + i) * KS_STR + h0];
                ra0[i] = t.h[0]; rb0[i] = t.h[1];
            }
            #pragma unroll
            for (int i = 8; i < 16; ++i) {
                U32H t; t.u = *(const unsigned int*)&Ks[(n0t + i) * KS_STR + h0];
                ra1[i - 8] = t.h[0]; rb1[i - 8] = t.h[1];
            }
            *(half8*)&Vt[(h0    ) * VT_STR + n0t    ] = ra0;
            *(half8*)&Vt[(h0    ) * VT_STR + n0t + 8] = ra1;
            *(half8*)&Vt[(h0 + 1) * VT_STR + n0t    ] = rb0;
            *(half8*)&Vt[(h0 + 1) * VT_STR + n0t + 8] = rb1;
        }
        __syncthreads();                 // Vt ready

        // ---- S^T = K . Q^T : tile nt covers keys nt*16+quad*4+r, col qrow=lc ----
        f32x4 S[4];
        #pragma unroll
        for (int nt = 0; nt < 4; ++nt) {
            f32x4 acc = zero4;
            #pragma unroll
            for (int s4 = 0; s4 < 4; ++s4) {
                half8 kf = *(half8*)&Ks[(nt * 16 + lc) * KS_STR + 32 * s4 + quad * 8];
                acc = __builtin_amdgcn_mfma_f32_16x16x32_f16(kf, qf[s4], acc, 0, 0, 0);
            }
            S[nt] = acc;
        }

        // ---- online softmax: reduce over keys = (regs, nt) in-lane + 2 shuffles ----
        float tmax = S[0][0];
        #pragma unroll
        for (int nt = 0; nt < 4; ++nt)
            #pragma unroll
            for (int r = 0; r < 4; ++r)
                tmax = fmaxf(tmax, S[nt][r]);
        tmax = fmaxf(tmax, __shfl_xor(tmax, 16, 64));
        tmax = fmaxf(tmax, __shfl_xor(tmax, 32, 64));

        const float nm = fmaxf(rmax, tmax);
        const float alpha = exp2f((rmax - nm) * L2E);
        rmax = nm;

        #pragma unroll
        for (int nt = 0; nt < 4; ++nt)
            #pragma unroll
            for (int r = 0; r < 4; ++r)
                S[nt][r] = exp2f((S[nt][r] - nm) * L2E);

        #pragma unroll
        for (int ct = 0; ct < 8; ++ct) O[ct] *= alpha;
        Osum *= alpha;

        // ---- P^T -> per-wave LDS as Ps[qrow][key] (contiguous both directions) ----
        #pragma unroll
        for (int nt = 0; nt < 4; ++nt) {
            half4 pv;
            pv[0] = (_Float16)S[nt][0]; pv[1] = (_Float16)S[nt][1];
            pv[2] = (_Float16)S[nt][2]; pv[3] = (_Float16)S[nt][3];
            *(half4*)&Ps[wave][lc * PS_STR + nt * 16 + quad * 4] = pv;
        }

        // ---- O^T += V^T . P^T ;  rowsum via ones-MFMA ----
        #pragma unroll
        for (int s2 = 0; s2 < 2; ++s2) {
            half8 pb = *(half8*)&Ps[wave][lc * PS_STR + s2 * 32 + quad * 8];
            Osum = __builtin_amdgcn_mfma_f32_16x16x32_f16(ones, pb, Osum, 0, 0, 0);
            #pragma unroll
            for (int ct = 0; ct < 8; ++ct) {
                half8 vf = *(half8*)&Vt[(ct * 16 + lc) * VT_STR + s2 * 32 + quad * 8];
                O[ct] = __builtin_amdgcn_mfma_f32_16x16x32_f16(vf, pb, O[ct], 0, 0, 0);
            }
        }
    }

    // ---- epilogue ----
    if (splits == 1) {
        const float inv = 1.0f / Osum[0];
        float* orow = out + ((size_t)b * QQ + m0 + wave * 16 + lc) * HH;
        #pragma unroll
        for (int ct = 0; ct < 8; ++ct) {
            f32x4 v = O[ct] * inv;
            *(f32x4*)&orow[ct * 16 + quad * 4] = v;
        }
    } else {
        float* po = ws + ((size_t)(s * 256 + r256)) * (BM * HH) + (wave * 16 + lc) * HH;
        #pragma unroll
        for (int ct = 0; ct < 8; ++ct)
            *(f32x4*)&po[ct * 16 + quad * 4] = O[ct];
        if (quad == 0) {
            const size_t mlBase = (size_t)splits * WS_O_FLOATS;
            const size_t idx = (size_t)(s * 256 + r256) * BM + wave * 16 + lc;
            ws[mlBase + idx] = rmax;
            ws[mlBase + (size_t)splits * WS_ML_FLOATS + idx] = Osum[0];
        }
    }
}

__global__ void attn_combine(const float* __restrict__ ws,
                             float* __restrict__ out,
                             int splits) {
    const int idx = blockIdx.x * 256 + threadIdx.x;   // over B*QQ*HH = 2^21
    const int h  = idx & 127;
    const int q  = (idx >> 7) & 2047;
    const int b  = idx >> 18;
    const int qb = q >> 6;
    const int qr = q & 63;
    const int blk = b * 32 + qb;

    const size_t mlBase = (size_t)splits * WS_O_FLOATS;
    const size_t lBase  = mlBase + (size_t)splits * WS_ML_FLOATS;

    float ms[4];
    float M = -3.0e38f;
    for (int s = 0; s < splits; ++s) {
        ms[s] = ws[mlBase + (size_t)(s * 256 + blk) * BM + qr];
        M = fmaxf(M, ms[s]);
    }
    float denom = 0.f, val = 0.f;
    for (int s = 0; s < splits; ++s) {
        const float w = exp2f((ms[s] - M) * L2E);
        denom += w * ws[lBase + (size_t)(s * 256 + blk) * BM + qr];
        val   += w * ws[(size_t)(s * 256 + blk) * (BM * HH) + qr * HH + h];
    }
    out[idx] = val / denom;
}

extern "C" void kernel_launch(void* const* d_in, const int* in_sizes, int n_in,
                              void* d_out, int out_size, void* d_ws, size_t ws_size,
                              hipStream_t stream) {
    const float* out_state = (const float*)d_in[0];
    const float* history   = (const float*)d_in[1];
    float* out = (float*)d_out;
    float* ws  = (float*)d_ws;

    const size_t needed = (size_t)SPLITS_TARGET * (WS_O_FLOATS + 2 * WS_ML_FLOATS) * 4;
    const int splits = (ws_size >= needed) ? SPLITS_TARGET : 1;

    attn_main<<<dim3(256 * splits), dim3(256), 0, stream>>>(out_state, history, out, ws, splits);
    if (splits > 1)
        attn_combine<<<dim3((8 * QQ * HH) / 256), dim3(256), 0, stream>>>(ws, out, splits);
}